// Round 1
// 1449.709 us; speedup vs baseline: 1.1463x; 1.1463x over previous
//
#include <hip/hip_runtime.h>
#include <math.h>

// ---------------- constants ----------------
static constexpr int BATCH = 2048;
static constexpr int E     = 128;
static constexpr int HDIM  = 1024;
static constexpr int V     = 100000;
static constexpr int NCT   = 782;        // ceil(V/128) col tiles
static constexpr int DIN   = 2048;       // (3*5+1)*E
static constexpr float EPS = 1e-5f;

// stats region float offsets
static constexpr int O_SSUM = 0;     // 16
static constexpr int O_SSQ  = 16;    // 16
static constexpr int O_ZDS  = 32;    // 128
static constexpr int O_ZDQ  = 160;   // 128
static constexpr int O_ZIS  = 288;   // 128
static constexpr int O_ZIQ  = 416;   // 128
static constexpr int O_H1S  = 544;   // 1024 (+1024 sq)
static constexpr int O_H2S  = 2592;  // 1024 (+1024 sq)
static constexpr int O_H3S  = 4640;  // 128 (+128 sq)

// ws byte offsets
static constexpr size_t OFF_STATS = 0;                         // 32 KB (zeroed)
static constexpr size_t OFF_H0   = 32768;                      // 2048*2048*2
static constexpr size_t OFF_W1B  = OFF_H0   + 8388608;         // 1024*2048*2
static constexpr size_t OFF_W2B  = OFF_W1B  + 4194304;         // 1024*1024*2
static constexpr size_t OFF_W3B  = OFF_W2B  + 2097152;         // 128*1024*2
static constexpr size_t OFF_EPB  = OFF_W3B  + 262144;          // (unused hole, kept for layout stability)
static constexpr size_t OFF_H1F  = OFF_EPB  + 25624576;        // 2048*1024*4
static constexpr size_t OFF_H1N  = OFF_H1F  + 8388608;         // 2048*1024*2
static constexpr size_t OFF_H2F  = OFF_H1N  + 4194304;
static constexpr size_t OFF_H2N  = OFF_H2F  + 8388608;
static constexpr size_t OFF_H3F  = OFF_H2N  + 4194304;         // 2048*128*4
static constexpr size_t OFF_H3N  = OFF_H3F  + 1048576;         // 2048*128*2
static constexpr size_t OFF_PMAX = OFF_H3N  + 524288;          // 782*2048*4
static constexpr size_t OFF_PSUM = OFF_PMAX + 6406144;
static constexpr size_t OFF_LSE  = OFF_PSUM + 6406144;         // 2048*4

typedef __bf16 bf16x8 __attribute__((ext_vector_type(8)));
typedef float  f32x4  __attribute__((ext_vector_type(4)));

__device__ __forceinline__ unsigned short f2bf(float f) {
    unsigned int u = __builtin_bit_cast(unsigned int, f);
    u += 0x7FFFu + ((u >> 16) & 1u);           // RNE
    return (unsigned short)(u >> 16);
}

// ---------------- fp32 -> bf16 convert ----------------
__global__ __launch_bounds__(256) void cvt_bf16(const float* __restrict__ s,
                                                unsigned short* __restrict__ d, int n4) {
    int i = blockIdx.x * 256 + threadIdx.x;
    int stride = gridDim.x * 256;
    for (; i < n4; i += stride) {
        float4 v = ((const float4*)s)[i];
        ushort4 o;
        o.x = f2bf(v.x); o.y = f2bf(v.y); o.z = f2bf(v.z); o.w = f2bf(v.w);
        ((ushort4*)d)[i] = o;
    }
}

// ---------------- branch stats (scalar feats cols, desc/imgs projected feats) ----------------
// 64 blocks x 32 rows each
__global__ __launch_bounds__(256) void stats1(const float* __restrict__ sf,
                                              const float* __restrict__ ldsc,
                                              const float* __restrict__ limg,
                                              const float* __restrict__ Wd,
                                              const float* __restrict__ Wi,
                                              float* __restrict__ stats) {
    __shared__ float redA[256], redB[256];
    const int t = threadIdx.x;
    const int r0 = blockIdx.x * 32;
    // scalar_feats column sums
    {
        int c = t & 15, rg = t >> 4;
        float s = 0.f, s2 = 0.f;
        for (int i = 0; i < 2; i++) {
            float v = sf[(size_t)(r0 + rg * 2 + i) * 16 + c];
            s += v; s2 += v * v;
        }
        redA[rg * 16 + c] = s; redB[rg * 16 + c] = s2;
        __syncthreads();
        if (t < 16) {
            float S = 0.f, Q = 0.f;
            for (int g = 0; g < 16; g++) { S += redA[g * 16 + t]; Q += redB[g * 16 + t]; }
            atomicAdd(&stats[O_SSUM + t], S);
            atomicAdd(&stats[O_SSQ + t], Q);
        }
        __syncthreads();
    }
    // desc (br=0) and imgs (br=1): per-feature stats of X @ W^T  (X:[B,8], W:[128,8])
    for (int br = 0; br < 2; br++) {
        const float* X = br ? limg : ldsc;
        const float* W = br ? Wi : Wd;
        int e = t & 127, rg = t >> 7;
        float wreg[8];
        #pragma unroll
        for (int k = 0; k < 8; k++) wreg[k] = W[e * 8 + k];
        float s = 0.f, s2 = 0.f;
        for (int i = 0; i < 16; i++) {
            int r = r0 + rg + 2 * i;
            float z = 0.f;
            #pragma unroll
            for (int k = 0; k < 8; k++) z += X[(size_t)r * 8 + k] * wreg[k];
            s += z; s2 += z * z;
        }
        redA[rg * 128 + e] = s; redB[rg * 128 + e] = s2;
        __syncthreads();
        if (t < 128) {
            int base = br ? O_ZIS : O_ZDS;
            atomicAdd(&stats[base + t], redA[t] + redA[128 + t]);
            atomicAdd(&stats[base + 128 + t], redB[t] + redB[128 + t]);
        }
        __syncthreads();
    }
}

// ---------------- build h0 = [lag_emb(5E) | cat_emb(5E) | url_emb(5E) | x(E)] in bf16 ----------------
__global__ __launch_bounds__(128) void build_h0_k(
    const float* __restrict__ sf, const float* __restrict__ ldsc, const float* __restrict__ limg,
    const int* __restrict__ lp, const int* __restrict__ fp, const int* __restrict__ lc,
    const int* __restrict__ fc, const int* __restrict__ lu, const int* __restrict__ fu,
    const int* __restrict__ cat,
    const float* __restrict__ eP, const float* __restrict__ eC, const float* __restrict__ eU,
    const float* __restrict__ eS,
    const float* __restrict__ Wsc, const float* __restrict__ gsc, const float* __restrict__ bsc,
    const float* __restrict__ Wd, const float* __restrict__ gd, const float* __restrict__ bd,
    const float* __restrict__ Wi, const float* __restrict__ gi, const float* __restrict__ bi,
    const float* __restrict__ stats, unsigned short* __restrict__ h0) {
    const int b = blockIdx.x, e = threadIdx.x;
    unsigned short* out = h0 + (size_t)b * DIN;
    #pragma unroll
    for (int j = 0; j < 5; j++) out[j * 128 + e] = f2bf(eP[(size_t)lp[b * 5 + j] * 128 + e]);
    #pragma unroll
    for (int j = 0; j < 5; j++) out[(5 + j) * 128 + e] = f2bf(eC[(size_t)lc[b * 5 + j] * 128 + e]);
    #pragma unroll
    for (int j = 0; j < 5; j++) out[(10 + j) * 128 + e] = f2bf(eU[(size_t)lu[b * 5 + j] * 128 + e]);
    float x = eP[(size_t)fp[b] * 128 + e] + eC[(size_t)fc[b] * 128 + e] + eU[(size_t)fu[b] * 128 + e];
    const int offs[7] = {0, 7, 31, 33, 37, 39, 41};
    #pragma unroll
    for (int j = 0; j < 7; j++) x += eS[(size_t)(offs[j] + cat[b * 7 + j]) * 128 + e];
    const float invB = 1.f / 2048.f;
    #pragma unroll
    for (int i = 0; i < 16; i++) {
        float ms = stats[O_SSUM + i] * invB;
        float vs = stats[O_SSQ + i] * invB - ms * ms;
        float wv = Wsc[i * 128 + e];
        float val = (sf[b * 16 + i] - ms) * wv * rsqrtf(vs * wv * wv + EPS) * gsc[i * 128 + e] + bsc[i * 128 + e];
        x += fmaxf(val, 0.f);
    }
    {
        float z = 0.f;
        #pragma unroll
        for (int k = 0; k < 8; k++) z += ldsc[b * 8 + k] * Wd[e * 8 + k];
        float md = stats[O_ZDS + e] * invB;
        float vd = stats[O_ZDQ + e] * invB - md * md;
        x += fmaxf((z - md) * rsqrtf(vd + EPS) * gd[e] + bd[e], 0.f);
    }
    {
        float z = 0.f;
        #pragma unroll
        for (int k = 0; k < 8; k++) z += limg[b * 8 + k] * Wi[e * 8 + k];
        float mi = stats[O_ZIS + e] * invB;
        float vi = stats[O_ZIQ + e] * invB - mi * mi;
        x += fmaxf((z - mi) * rsqrtf(vi + EPS) * gi[e] + bi[e], 0.f);
    }
    out[15 * 128 + e] = f2bf(x);
}

// ---------------- GEMM  C = A(bf16,[M,K]) * B(bf16,[N,K])^T  (MODE 0 only used) ----------------
template <int BM, int BN, int MODE>
__global__ __launch_bounds__(256) void gemm_bt(
    const unsigned short* __restrict__ A, int lda,
    const unsigned short* __restrict__ Bm, int ldb,
    const float* __restrict__ bias,
    float* __restrict__ C, int ldc, int K,
    float* __restrict__ pmax, float* __restrict__ psum) {
    constexpr int WM = BM / 2, WN = BN / 2, TI = WM / 16, TJ = WN / 16;
    __shared__ uint4 sA[BM * 4];
    __shared__ uint4 sB[BN * 4];
    const int t = threadIdx.x;
    const int w = t >> 6, lane = t & 63;
    const int wr = w >> 1, wc = w & 1;
    const int m16 = lane & 15, q = lane >> 4;
    const int m0 = blockIdx.y * BM, n0 = blockIdx.x * BN;

    f32x4 acc[TI][TJ];
    #pragma unroll
    for (int i = 0; i < TI; i++)
        #pragma unroll
        for (int j = 0; j < TJ; j++) acc[i][j] = (f32x4){0.f, 0.f, 0.f, 0.f};

    for (int k0 = 0; k0 < K; k0 += 32) {
        __syncthreads();
        for (int c = t; c < (BM + BN) * 4; c += 256) {
            int isB = c >= BM * 4;
            int cc = isB ? c - BM * 4 : c;
            int row = cc >> 2, kc = cc & 3;
            const unsigned short* src = isB ? (Bm + (size_t)(n0 + row) * ldb + k0)
                                            : (A + (size_t)(m0 + row) * lda + k0);
            uint4 v = ((const uint4*)src)[kc];
            int pos = row * 4 + (kc ^ ((row >> 1) & 3));   // XOR swizzle vs banks
            (isB ? sB : sA)[pos] = v;
        }
        __syncthreads();
        bf16x8 aF[TI], bF[TJ];
        #pragma unroll
        for (int i = 0; i < TI; i++) {
            int row = wr * WM + i * 16 + m16;
            aF[i] = ((const bf16x8*)sA)[row * 4 + (q ^ ((row >> 1) & 3))];
        }
        #pragma unroll
        for (int j = 0; j < TJ; j++) {
            int row = wc * WN + j * 16 + m16;
            bF[j] = ((const bf16x8*)sB)[row * 4 + (q ^ ((row >> 1) & 3))];
        }
        #pragma unroll
        for (int i = 0; i < TI; i++)
            #pragma unroll
            for (int j = 0; j < TJ; j++)
                acc[i][j] = __builtin_amdgcn_mfma_f32_16x16x32_bf16(aF[i], bF[j], acc[i][j], 0, 0, 0);
    }

    #pragma unroll
    for (int j = 0; j < TJ; j++) {
        int col = n0 + wc * WN + j * 16 + m16;
        float bv = bias[col];
        #pragma unroll
        for (int i = 0; i < TI; i++)
            #pragma unroll
            for (int r = 0; r < 4; r++) {
                int row = m0 + wr * WM + i * 16 + q * 4 + r;
                C[(size_t)row * ldc + col] = acc[i][j][r] + bv;
            }
    }
}

// ---------------- tied-weight logits + fused partial softmax ----------------
// grid (NCT, 2), 256 threads. One block owns one 128-col tile of eP (staged ONCE,
// fp32->bf16 in-kernel) and loops over 8 row-tiles of h3n (reg-staged, prefetch
// overlapped with the exp/store epilogue).
__global__ __launch_bounds__(256, 2) void logits_k(
    const unsigned short* __restrict__ A,   // h3n bf16 [2048][128]
    const float* __restrict__ eP,           // fp32 [V][128]
    const float* __restrict__ bias,         // [V]
    float* __restrict__ C,                  // [2048][V]
    float* __restrict__ pmax, float* __restrict__ psum) {
    __shared__ uint4 sB[2048];   // 32 KB: [128 cols][16 chunks] swizzled, K=128 resident
    __shared__ uint4 sA[2048];   // 32 KB: current A row-tile
    __shared__ float sred[640];  // srmax[256] | srsum[256] | sM[128]
    float* srmax = sred;
    float* srsum = sred + 256;
    float* sM    = sred + 512;

    const int t = threadIdx.x;
    const int w = t >> 6, lane = t & 63;
    const int wr = w >> 1, wc = w & 1;
    const int m16 = lane & 15, q = lane >> 4;
    const int n0 = blockIdx.x * 128;
    const int mbase = blockIdx.y * 1024;      // 8 row-tiles of 128

    uint4 av[8];
    // ---- A(tile 0) global -> regs (swizzled source, linear LDS dest) ----
    #pragma unroll
    for (int i = 0; i < 8; i++) {
        int c = i * 256 + t, row = c >> 4, ch = c & 15;
        av[i] = ((const uint4*)(A + (size_t)(mbase + row) * 128))[ch ^ (row & 7)];
    }
    // ---- B tile: eP fp32 -> bf16, swizzled (read-once; kills cvt pass + restaging) ----
    #pragma unroll
    for (int i = 0; i < 8; i++) {
        int c = i * 256 + t, row = c >> 4, ch = c & 15;
        int gc = n0 + row, sc = ch ^ (row & 7);
        uint4 v = {0u, 0u, 0u, 0u};
        if (gc < V) {
            const float4* p = (const float4*)(eP + (size_t)gc * 128 + sc * 8);
            float4 f0 = p[0], f1 = p[1];
            v.x = (unsigned)f2bf(f0.x) | ((unsigned)f2bf(f0.y) << 16);
            v.y = (unsigned)f2bf(f0.z) | ((unsigned)f2bf(f0.w) << 16);
            v.z = (unsigned)f2bf(f1.x) | ((unsigned)f2bf(f1.y) << 16);
            v.w = (unsigned)f2bf(f1.z) | ((unsigned)f2bf(f1.w) << 16);
        }
        sB[row * 16 + ch] = v;
    }
    #pragma unroll
    for (int i = 0; i < 8; i++) sA[i * 256 + t] = av[i];

    // bias per column (fixed for the whole block)
    float bias_j[4]; bool val_j[4];
    const int colbase = n0 + wc * 64;
    #pragma unroll
    for (int j = 0; j < 4; j++) {
        int col = colbase + j * 16 + m16;
        val_j[j] = (col < V);
        bias_j[j] = val_j[j] ? bias[col] : 0.f;
    }
    __syncthreads();

    for (int mt = 0; mt < 8; ++mt) {
        const int m0 = mbase + mt * 128;
        f32x4 acc[4][4];
        #pragma unroll
        for (int i = 0; i < 4; i++)
            #pragma unroll
            for (int j = 0; j < 4; j++) acc[i][j] = (f32x4){0.f, 0.f, 0.f, 0.f};
        #pragma unroll
        for (int kk = 0; kk < 4; kk++) {
            bf16x8 aF[4], bF[4];
            #pragma unroll
            for (int i = 0; i < 4; i++) {
                int row = wr * 64 + i * 16 + m16;
                aF[i] = ((const bf16x8*)sA)[row * 16 + ((kk * 4 + q) ^ (row & 7))];
            }
            #pragma unroll
            for (int j = 0; j < 4; j++) {
                int row = wc * 64 + j * 16 + m16;
                bF[j] = ((const bf16x8*)sB)[row * 16 + ((kk * 4 + q) ^ (row & 7))];
            }
            #pragma unroll
            for (int i = 0; i < 4; i++)
                #pragma unroll
                for (int j = 0; j < 4; j++)
                    acc[i][j] = __builtin_amdgcn_mfma_f32_16x16x32_bf16(aF[i], bF[j], acc[i][j], 0, 0, 0);
        }
        // ---- row maxes over this 128-col tile ----
        #pragma unroll
        for (int i = 0; i < 4; i++)
            #pragma unroll
            for (int r = 0; r < 4; r++) {
                int rowb = wr * 64 + i * 16 + q * 4 + r;
                float mx = -INFINITY;
                #pragma unroll
                for (int j = 0; j < 4; j++)
                    if (val_j[j]) mx = fmaxf(mx, acc[i][j][r] + bias_j[j]);
                #pragma unroll
                for (int msk = 1; msk < 16; msk <<= 1) mx = fmaxf(mx, __shfl_xor(mx, msk, 64));
                if (m16 == 0) srmax[rowb * 2 + wc] = mx;
            }
        __syncthreads();                       // (a) frag reads + srmax done -> sA free
        if (t < 128) sM[t] = fmaxf(srmax[t * 2], srmax[t * 2 + 1]);
        __syncthreads();                       // (b)
        if (mt + 1 < 8) {                      // prefetch next A tile; lands under exp/store
            #pragma unroll
            for (int i = 0; i < 8; i++) {
                int c = i * 256 + t, row = c >> 4, ch = c & 15;
                av[i] = ((const uint4*)(A + (size_t)(m0 + 128 + row) * 128))[ch ^ (row & 7)];
            }
        }
        // ---- exp-sums + logits store ----
        #pragma unroll
        for (int i = 0; i < 4; i++)
            #pragma unroll
            for (int r = 0; r < 4; r++) {
                int rowb = wr * 64 + i * 16 + q * 4 + r;
                int grow = m0 + rowb;
                float Mr = sM[rowb];
                float sm_ = 0.f;
                #pragma unroll
                for (int j = 0; j < 4; j++)
                    if (val_j[j]) {
                        float v = acc[i][j][r] + bias_j[j];
                        C[(size_t)grow * V + colbase + j * 16 + m16] = v;
                        sm_ += __expf(v - Mr);
                    }
                #pragma unroll
                for (int msk = 1; msk < 16; msk <<= 1) sm_ += __shfl_xor(sm_, msk, 64);
                if (m16 == 0) srsum[rowb * 2 + wc] = sm_;
            }
        __syncthreads();                       // (c)
        if (t < 128) {
            pmax[(size_t)blockIdx.x * BATCH + m0 + t] = sM[t];
            psum[(size_t)blockIdx.x * BATCH + m0 + t] = srsum[t * 2] + srsum[t * 2 + 1];
        }
        if (mt + 1 < 8) {
            #pragma unroll
            for (int i = 0; i < 8; i++) sA[i * 256 + t] = av[i];
        }
        __syncthreads();                       // (d) next A tile visible
    }
}

// ---------------- column stats of fp32 [2048, N]: sums[col], sums[N+col] ----------------
__global__ __launch_bounds__(256) void colstats(const float* __restrict__ X,
                                                float* __restrict__ sums, int N) {
    int c = threadIdx.x & 63, rg = threadIdx.x >> 6;
    int col = blockIdx.x * 64 + c;
    int r0 = blockIdx.y * 128 + rg * 32;
    float s = 0.f, s2 = 0.f;
    for (int i = 0; i < 32; i++) {
        float v = X[(size_t)(r0 + i) * N + col];
        s += v; s2 += v * v;
    }
    __shared__ float rs[4][64], rq[4][64];
    rs[rg][c] = s; rq[rg][c] = s2;
    __syncthreads();
    if (threadIdx.x < 64) {
        float S = 0.f, Q = 0.f;
        for (int g = 0; g < 4; g++) { S += rs[g][threadIdx.x]; Q += rq[g][threadIdx.x]; }
        atomicAdd(&sums[col], S);
        atomicAdd(&sums[N + col], Q);
    }
}

// ---------------- BN (batch stats) + PReLU -> bf16 ----------------
__global__ __launch_bounds__(256) void bn_prelu(const float* __restrict__ X,
                                                unsigned short* __restrict__ Y,
                                                const float* __restrict__ sums,
                                                const float* __restrict__ g,
                                                const float* __restrict__ be,
                                                const float* __restrict__ p, int N, int total4) {
    int i = blockIdx.x * 256 + threadIdx.x;
    if (i >= total4) return;
    float pv = p[0];
    int n4 = N >> 2;
    int c4 = i % n4;
    float4 v = ((const float4*)X)[i];
    float vv[4] = {v.x, v.y, v.z, v.w};
    unsigned short oo[4];
    #pragma unroll
    for (int k = 0; k < 4; k++) {
        int n = c4 * 4 + k;
        float m = sums[n] * (1.f / 2048.f);
        float var = sums[N + n] * (1.f / 2048.f) - m * m;
        float val = (vv[k] - m) * rsqrtf(var + EPS) * g[n] + be[n];
        val = val > 0.f ? val : pv * val;
        oo[k] = f2bf(val);
    }
    ushort4 o; o.x = oo[0]; o.y = oo[1]; o.z = oo[2]; o.w = oo[3];
    ((ushort4*)Y)[i] = o;
}

// ---------------- merge per-tile (max,sumexp) -> lse per row ----------------
// 32 blocks x 256 threads; 4-way tile-chunk split per 64-row group.
__global__ __launch_bounds__(256) void lse_k(const float* __restrict__ pmax,
                                             const float* __restrict__ psum,
                                             float* __restrict__ lse, int ntiles) {
    __shared__ float shm[4 * 64], shs[4 * 64];
    int lr = threadIdx.x & 63;
    int ch = threadIdx.x >> 6;
    int r = blockIdx.x * 64 + lr;
    int per = (ntiles + 3) >> 2;
    int t0 = ch * per, t1 = t0 + per;
    if (t1 > ntiles) t1 = ntiles;
    float m = -INFINITY, s = 0.f;
    for (int tt = t0; tt < t1; ++tt) {
        float pm = pmax[(size_t)tt * BATCH + r];
        float ps = psum[(size_t)tt * BATCH + r];
        if (pm > m) { s = s * __expf(m - pm) + ps; m = pm; }
        else        { s += ps * __expf(pm - m); }
    }
    shm[ch * 64 + lr] = m; shs[ch * 64 + lr] = s;
    __syncthreads();
    if (threadIdx.x < 64) {
        float M = shm[lr], S = shs[lr];
        #pragma unroll
        for (int g = 1; g < 4; ++g) {
            float pm = shm[g * 64 + lr], ps = shs[g * 64 + lr];
            if (pm > M) { S = S * __expf(M - pm) + ps; M = pm; }
            else        { S += ps * __expf(pm - M); }
        }
        lse[blockIdx.x * 64 + lr] = M + __logf(S);
    }
}

// ---------------- masked mean NLL ----------------
__global__ __launch_bounds__(256) void loss_k(const float* __restrict__ logits,
                                              const float* __restrict__ lse,
                                              const int* __restrict__ target,
                                              float* __restrict__ out_loss) {
    int t = threadIdx.x;
    float s = 0.f, c = 0.f;
    for (int r = t; r < BATCH; r += 256) {
        int tg = target[r];
        if (tg != 0) {
            s += lse[r] - logits[(size_t)r * V + tg];
            c += 1.f;
        }
    }
    #pragma unroll
    for (int m = 1; m < 64; m <<= 1) { s += __shfl_xor(s, m, 64); c += __shfl_xor(c, m, 64); }
    __shared__ float ss[4], sc[4];
    if ((t & 63) == 0) { ss[t >> 6] = s; sc[t >> 6] = c; }
    __syncthreads();
    if (t == 0) {
        float S = ss[0] + ss[1] + ss[2] + ss[3];
        float C = sc[0] + sc[1] + sc[2] + sc[3];
        out_loss[0] = S / C;
    }
}

// ---------------- launch ----------------
extern "C" void kernel_launch(void* const* d_in, const int* in_sizes, int n_in,
                              void* d_out, int out_size, void* d_ws, size_t ws_size,
                              hipStream_t stream) {
    const float* sf   = (const float*)d_in[0];
    const float* ldsc = (const float*)d_in[1];
    const float* limg = (const float*)d_in[2];
    const int* lp  = (const int*)d_in[3];
    const int* fp  = (const int*)d_in[4];
    const int* lc  = (const int*)d_in[5];
    const int* fc  = (const int*)d_in[6];
    const int* lu  = (const int*)d_in[7];
    const int* fu  = (const int*)d_in[8];
    const int* cat = (const int*)d_in[9];
    const int* tgt = (const int*)d_in[10];
    const float* eP  = (const float*)d_in[11];
    const float* eC  = (const float*)d_in[12];
    const float* eU  = (const float*)d_in[13];
    const float* eS  = (const float*)d_in[14];
    const float* Wsc = (const float*)d_in[15];
    const float* gsc = (const float*)d_in[16];
    const float* bsc = (const float*)d_in[17];
    const float* Wd  = (const float*)d_in[18];
    const float* gd  = (const float*)d_in[19];
    const float* bd  = (const float*)d_in[20];
    const float* Wi  = (const float*)d_in[21];
    const float* gi  = (const float*)d_in[22];
    const float* bi  = (const float*)d_in[23];
    const float* W1  = (const float*)d_in[24];
    const float* b1  = (const float*)d_in[25];
    const float* g1  = (const float*)d_in[26];
    const float* be1 = (const float*)d_in[27];
    const float* p1  = (const float*)d_in[28];
    const float* W2  = (const float*)d_in[29];
    const float* b2  = (const float*)d_in[30];
    const float* g2  = (const float*)d_in[31];
    const float* be2 = (const float*)d_in[32];
    const float* p2  = (const float*)d_in[33];
    const float* W3  = (const float*)d_in[34];
    const float* b3  = (const float*)d_in[35];
    const float* g3  = (const float*)d_in[36];
    const float* be3 = (const float*)d_in[37];
    const float* p3  = (const float*)d_in[38];
    const float* ob  = (const float*)d_in[39];

    char* w = (char*)d_ws;
    float* stats = (float*)(w + OFF_STATS);
    unsigned short* h0  = (unsigned short*)(w + OFF_H0);
    unsigned short* W1b = (unsigned short*)(w + OFF_W1B);
    unsigned short* W2b = (unsigned short*)(w + OFF_W2B);
    unsigned short* W3b = (unsigned short*)(w + OFF_W3B);
    float* h1f = (float*)(w + OFF_H1F);
    unsigned short* h1n = (unsigned short*)(w + OFF_H1N);
    float* h2f = (float*)(w + OFF_H2F);
    unsigned short* h2n = (unsigned short*)(w + OFF_H2N);
    float* h3f = (float*)(w + OFF_H3F);
    unsigned short* h3n = (unsigned short*)(w + OFF_H3N);
    float* pmaxb = (float*)(w + OFF_PMAX);
    float* psumb = (float*)(w + OFF_PSUM);
    float* lseb  = (float*)(w + OFF_LSE);
    float* logits = (float*)d_out;

    hipMemsetAsync(stats, 0, 32768, stream);

    cvt_bf16<<<512, 256, 0, stream>>>(W1, W1b, (HDIM * DIN) / 4);
    cvt_bf16<<<512, 256, 0, stream>>>(W2, W2b, (HDIM * HDIM) / 4);
    cvt_bf16<<<128, 256, 0, stream>>>(W3, W3b, (E * HDIM) / 4);

    stats1<<<64, 256, 0, stream>>>(sf, ldsc, limg, Wd, Wi, stats);

    build_h0_k<<<BATCH, 128, 0, stream>>>(sf, ldsc, limg, lp, fp, lc, fc, lu, fu, cat,
                                          eP, eC, eU, eS, Wsc, gsc, bsc, Wd, gd, bd,
                                          Wi, gi, bi, stats, h0);

    gemm_bt<128, 64, 0><<<dim3(HDIM / 64, BATCH / 128), 256, 0, stream>>>(
        h0, DIN, W1b, DIN, b1, h1f, HDIM, DIN, nullptr, nullptr);
    colstats<<<dim3(HDIM / 64, 16), 256, 0, stream>>>(h1f, stats + O_H1S, HDIM);
    bn_prelu<<<(BATCH * HDIM / 4) / 256, 256, 0, stream>>>(h1f, h1n, stats + O_H1S, g1, be1, p1,
                                                           HDIM, BATCH * HDIM / 4);

    gemm_bt<128, 64, 0><<<dim3(HDIM / 64, BATCH / 128), 256, 0, stream>>>(
        h1n, HDIM, W2b, HDIM, b2, h2f, HDIM, HDIM, nullptr, nullptr);
    colstats<<<dim3(HDIM / 64, 16), 256, 0, stream>>>(h2f, stats + O_H2S, HDIM);
    bn_prelu<<<(BATCH * HDIM / 4) / 256, 256, 0, stream>>>(h2f, h2n, stats + O_H2S, g2, be2, p2,
                                                           HDIM, BATCH * HDIM / 4);

    gemm_bt<64, 32, 0><<<dim3(E / 32, BATCH / 64), 256, 0, stream>>>(
        h2n, HDIM, W3b, HDIM, b3, h3f, E, HDIM, nullptr, nullptr);
    colstats<<<dim3(E / 64, 16), 256, 0, stream>>>(h3f, stats + O_H3S, E);
    bn_prelu<<<(BATCH * E / 4) / 256, 256, 0, stream>>>(h3f, h3n, stats + O_H3S, g3, be3, p3,
                                                        E, BATCH * E / 4);

    logits_k<<<dim3(NCT, 2), 256, 0, stream>>>(h3n, eP, ob, logits, pmaxb, psumb);

    lse_k<<<BATCH / 64, 256, 0, stream>>>(pmaxb, psumb, lseb, NCT);
    loss_k<<<1, 256, 0, stream>>>(logits, lseb, tgt, logits + (size_t)BATCH * V);
}